// Round 11
// baseline (177.391 us; speedup 1.0000x reference)
//
#include <hip/hip_runtime.h>
#include <stdint.h>

typedef unsigned short u16;
typedef __attribute__((ext_vector_type(8))) short short8;   // 8 bf16 (4 VGPRs) MFMA A/B frag K=32
typedef __attribute__((ext_vector_type(4))) short short4v;  // 4 bf16 (2 VGPRs) MFMA A/B frag K=16
typedef __attribute__((ext_vector_type(4))) float float4v;  // MFMA C/D frag

#define NB 2
#define NT 2048
#define NC 1024
#define NH 16
#define ND 64
#define NM (NB*NT)   // 4096 rows total

// 16x16x16 bf16 MFMA (2-VGPR operands). Builtin if present, else raw asm.
#if defined(__has_builtin)
#if __has_builtin(__builtin_amdgcn_mfma_f32_16x16x16bf16_1k)
#define MFMA16(a, b, c) __builtin_amdgcn_mfma_f32_16x16x16bf16_1k(a, b, c, 0, 0, 0)
#endif
#endif
#ifndef MFMA16
static __device__ __forceinline__ float4v mfma16_asm(short4v a, short4v b, float4v c) {
  asm volatile("v_mfma_f32_16x16x16_bf16 %0, %1, %2, %0" : "+v"(c) : "v"(a), "v"(b));
  return c;
}
#define MFMA16(a, b, c) mfma16_asm(a, b, c)
#endif

// fast exp2: bare v_exp_f32 (ocml exp2f adds denorm-range fixup we don't need).
#if defined(__has_builtin)
#if __has_builtin(__builtin_amdgcn_exp2f)
#define EXP2(x) __builtin_amdgcn_exp2f(x)
#endif
#endif
#ifndef EXP2
extern "C" __device__ float __ocml_native_exp2_f32(float);
#define EXP2(x) __ocml_native_exp2_f32(x)
#endif

// SINGLE-BARRIER pipelined loop idiom:
//   [waitcnt vmcnt(0) -> own stage(k) landed] [s_barrier] [stage(k+1) into p^1]
//   [compute on p]. BK=64 compute phase covers HBM latency.
// r9 lesson: device-scope __threadfence per block costs ~0.2us in cross-XCD L2
// writebacks -- launch boundaries (~5us) are cheaper. Keep combine separate.
// r10 lesson: shrinking per-block work for occupancy regresses when it halves
// the latency-covering compute phase without fixing dispatch raggedness.
#define WB0 asm volatile("s_waitcnt vmcnt(0)\n\ts_barrier" ::: "memory")
#define BAR_PLAIN asm volatile("s_barrier" ::: "memory")

// fp32 -> bf16 round-to-nearest-even
__device__ __forceinline__ u16 f2bf(float f) {
  union { float f; uint32_t u; } v; v.f = f;
  uint32_t u = v.u;
  u += 0x7fffu + ((u >> 16) & 1u);
  return (u16)(u >> 16);
}
__device__ __forceinline__ float bf2f(u16 u) {
  union { uint32_t u; float f; } v; v.u = ((uint32_t)u) << 16; return v.f;
}

// pack 4 fp32 -> 4 bf16 (truncation) via 2 v_perm_b32
__device__ __forceinline__ short4v pack4bf(float a, float b, float c, float d) {
  union { uint32_t u[2]; short4v s; } r;
  r.u[0] = __builtin_amdgcn_perm(__float_as_uint(b), __float_as_uint(a), 0x07060302u);
  r.u[1] = __builtin_amdgcn_perm(__float_as_uint(d), __float_as_uint(c), 0x07060302u);
  return r.s;
}

// async global->LDS, 16B per lane; lds dest wave-uniform (lane i -> lds + i*16B)
__device__ __forceinline__ void gld_lds16(const u16* g, u16* lds) {
  __builtin_amdgcn_global_load_lds(
      (const __attribute__((address_space(1))) uint32_t*)g,
      (__attribute__((address_space(3))) uint32_t*)lds,
      16, 0, 0);
}

// ---------------- cast: x, Wk, Wq, Wv, Wp -> bf16 ----------------
__global__ __launch_bounds__(256) void cast_all(
    const float* __restrict__ x,  const float* __restrict__ wk,
    const float* __restrict__ wq, const float* __restrict__ wv,
    const float* __restrict__ wp,
    u16* __restrict__ xb, u16* __restrict__ wkb, u16* __restrict__ wqb,
    u16* __restrict__ wvb, u16* __restrict__ wpb) {
  const int NX = NM * NC / 4;
  const int NW = NC * NC / 4;
  int i = blockIdx.x * 256 + threadIdx.x;
  const float* src; u16* dst; int off;
  if (i < NX)            { src = x;  dst = xb;  off = i; }
  else if (i < NX+NW)    { src = wk; dst = wkb; off = i - NX; }
  else if (i < NX+2*NW)  { src = wq; dst = wqb; off = i - NX - NW; }
  else if (i < NX+3*NW)  { src = wv; dst = wvb; off = i - NX - 2*NW; }
  else if (i < NX+4*NW)  { src = wp; dst = wpb; off = i - NX - 3*NW; }
  else return;
  float4v f = ((const float4v*)src)[off];
  short4v o;
  o.x = (short)f2bf(f.x); o.y = (short)f2bf(f.y);
  o.z = (short)f2bf(f.z); o.w = (short)f2bf(f.w);
  ((short4v*)dst)[off] = o;
}

// ---------------- fused QKV projection + in-kernel V transpose (PIPELINED) ----------
// RETILED 128x128 -> 128x64: grid 1536 = 8 XCD-groups x 4 m x 16 n x 3 mats.
// LDS 48 KB (A 32K dbuf + B 16K dbuf) -> 3 blocks/CU -> 768 concurrent = exactly
// 2 EVEN dispatch rounds (was 768 blocks at 2/CU = 1.5 ragged rounds, last 256
// blocks ran on a half-idle machine). M=128 kept so the V-transpose permutation
// (off = wm*64+quad*16+mt*4+r) and attn's matching PV layout are unchanged.
// BK=64: 16 K-steps; single barrier per K-step. Q pre-scaled by 0.125*log2e.
__global__ __launch_bounds__(256, 3) void qkv_gemm(
    const u16* __restrict__ xb,
    const u16* __restrict__ wqb, const u16* __restrict__ wkb, const u16* __restrict__ wvb,
    const float* __restrict__ bq, const float* __restrict__ bk, const float* __restrict__ bv,
    u16* __restrict__ Q, u16* __restrict__ K, u16* __restrict__ Vt) {
  __shared__ u16 SA[2][128 * 64];    // 32 KB
  __shared__ u16 SB[2][64 * 64];     // 16 KB
  const int id  = blockIdx.x;        // 0..1535
  const int mg  = id & 7;            // XCD-owned m-group
  const int mti = mg * 4 + ((id >> 3) & 3);   // m tile 0..31
  const int rr  = id >> 5;           // 0..47
  const int x16 = rr & 15;           // n tile (64 cols)
  const int mat = rr >> 4;           // 0=Q 1=K 2=V
  const int n0  = x16 * 64;
  const int m0  = mti * 128;
  const u16*   W    = (mat == 0) ? wqb : (mat == 1) ? wkb : wvb;
  const float* bias = (mat == 0) ? bq  : (mat == 1) ? bk  : bv;

  const int tid = threadIdx.x, wave = tid >> 6, lane = tid & 63;
  const int quad = lane >> 4, l15 = lane & 15;
  const int wm = wave >> 1, wn = wave & 1;   // wave-tile 64x32

  const u16* A_tile = xb + (size_t)m0 * NC;
  const u16* W_tile = W  + (size_t)n0 * NC;

  // staging: lane -> row (lane>>3), chunk (lane&7)^(row&7). A: 4 slabs of 32
  // rows (128); B: 2 slabs (64).
  const int srow = (lane >> 3);
  const int sgc  = (lane & 7) ^ srow;
  int sOff[4], sLds[4];
#pragma unroll
  for (int ii = 0; ii < 4; ii++) {
    int row_l = ii * 32 + wave * 8 + srow;
    sOff[ii] = row_l * NC + sgc * 8;
    sLds[ii] = (ii * 32 + wave * 8) * 64;    // wave-uniform LDS base (u16)
  }

  float4v acc[4][2];
#pragma unroll
  for (int i = 0; i < 4; i++)
#pragma unroll
    for (int j = 0; j < 2; j++) acc[i][j] = (float4v){0.f, 0.f, 0.f, 0.f};

  auto stage = [&](int ki, int p) {
    const u16* a = A_tile + ki * 64;
    const u16* w = W_tile + ki * 64;
#pragma unroll
    for (int ii = 0; ii < 4; ii++)
      gld_lds16(a + sOff[ii], SA[p] + sLds[ii]);
#pragma unroll
    for (int ii = 0; ii < 2; ii++)
      gld_lds16(w + sOff[ii], SB[p] + sLds[ii]);
  };

  stage(0, 0);
  for (int ki = 0; ki < 16; ki++) {
    const int p = ki & 1;
    WB0;                            // own stage(ki) drained, then barrier
    if (ki < 15) stage(ki + 1, p ^ 1);   // overwrite p^1: readers passed barrier
    const u16* As = SA[p];
    const u16* Bs = SB[p];
#pragma unroll
    for (int kk = 0; kk < 2; kk++) {
      short8 af[4], bf[2];
#pragma unroll
      for (int mt = 0; mt < 4; mt++) {
        int row = wm * 64 + mt * 16 + l15;
        int e   = (kk * 4 + quad) ^ (row & 7);
        af[mt] = *(const short8*)(As + row * 64 + e * 8);
      }
#pragma unroll
      for (int nt = 0; nt < 2; nt++) {
        int row = wn * 32 + nt * 16 + l15;
        int e   = (kk * 4 + quad) ^ (row & 7);
        bf[nt] = *(const short8*)(Bs + row * 64 + e * 8);
      }
#pragma unroll
      for (int mt = 0; mt < 4; mt++)
#pragma unroll
        for (int nt = 0; nt < 2; nt++)
          acc[mt][nt] = __builtin_amdgcn_mfma_f32_16x16x32_bf16(af[mt], bf[nt], acc[mt][nt], 0, 0, 0);
    }
  }

  if (mat != 2) {
    // Q/K: repack via LDS [128][64] (XOR chunk-swizzle by (row>>2)&7), then
    // coalesced 16B stores.
    u16* dst = (mat == 0) ? Q : K;
    const float osc = (mat == 0) ? 0.18033688f : 1.0f;   // fold 0.125*log2(e) into Q
    BAR_PLAIN;                       // all waves done reading LDS before reuse
    u16* tile = (u16*)SA;
#pragma unroll
    for (int nt = 0; nt < 2; nt++) {
      int col = wn * 32 + nt * 16 + l15;   // 0..63
      float bval = bias[n0 + col];
#pragma unroll
      for (int mt = 0; mt < 4; mt++) {
        int rowb = wm * 64 + mt * 16 + quad * 4;
#pragma unroll
        for (int r = 0; r < 4; r++) {
          int row = rowb + r;
          tile[row * 64 + (col ^ (((row >> 2) & 7) << 3))] =
              f2bf((acc[mt][nt][r] + bval) * osc);
        }
      }
    }
    __syncthreads();
#pragma unroll
    for (int it = 0; it < 4; it++) {
      int idx = it * 256 + tid;      // 0..1023: 128 rows x 8 col-chunks of 16B
      int row = idx >> 3, ck = idx & 7;
      int s = (row >> 2) & 7;
      short8 v = *(const short8*)(tile + row * 64 + ((ck ^ s) << 3));
      *(short8*)(dst + (size_t)(m0 + row) * NC + n0 + ck * 8) = v;
    }
  } else {
    // V: transpose + s-permute via LDS. tile[c][off]: c = d (one head, 64),
    // off = permuted t position (128) = wm*64+quad*16+mt*4+r -- IDENTICAL to
    // the 128-wide version, so global Vt layout (and attn's PV reads) unchanged.
    BAR_PLAIN;
    u16* tile = (u16*)SA;            // 64 x 128 u16 = 16 KB
#pragma unroll
    for (int nt = 0; nt < 2; nt++) {
      int c = wn * 32 + nt * 16 + l15;     // 0..63 = d
      float bval = bias[n0 + c];
#pragma unroll
      for (int mt = 0; mt < 4; mt++) {
#pragma unroll
        for (int r = 0; r < 4; r++) {
          int mr  = mt * 4 + r;
          int off = wm * 64 + quad * 16 + mr;          // permuted t position
          int ck  = (off >> 3) ^ (c & 15);
          tile[c * 128 + ck * 8 + (off & 7)] = f2bf(acc[mt][nt][r] + bval);
        }
      }
    }
    __syncthreads();
    const int b  = m0 >> 11, t0 = m0 & 2047;
    const int bh = b * NH + (n0 >> 6);     // single head for this n-tile
#pragma unroll
    for (int it = 0; it < 4; it++) {
      int idx = it * 256 + tid;      // 0..1023: 64 c x 16 t-chunks of 16B
      int c = idx >> 4, ck = idx & 15;
      short8 v = *(const short8*)(tile + c * 128 + ((ck ^ (c & 15)) * 8));
      *(short8*)(Vt + ((size_t)bh * ND + c) * NT + t0 + ck * 8) = v;
    }
  }
}

// ---------------- flash attention (causal), fixed-max softmax, 32 classes/bh ----
// 4 waves x 32 q-rows; single barrier per kv-tile; l on MFMA pipe; setprio(1);
// fully-masked-tile skip + diagonal peel (r6 structure, best measured).
__global__ __launch_bounds__(256, 4) void attn(
    const u16* __restrict__ Q, const u16* __restrict__ K,
    const u16* __restrict__ Vt, u16* __restrict__ O,
    u16* __restrict__ Opart, float* __restrict__ Lpart) {
  __shared__ u16 Kc[2][64 * 64];   // [s][d] swizzled
  __shared__ u16 Vc[2][64 * 64];   // [d][pos(s)] swizzled

  const int tid = threadIdx.x, wave = tid >> 6, lane = tid & 63;
  const int quad = lane >> 4, l15 = lane & 15;
  const int c8 = lane & 7, r8 = lane >> 3;
  const int id = blockIdx.x;
  const int gq = (id >> 3) & 31;   // class-group (same for a CU's 4 blocks)
  const int gp = id >> 8;          // pass 0..3
  static const uint8_t QT[8][4] = {
      {15, 16, 4, 0}, {30, 31, 3, 1}, {13, 14, 9, 2}, {25, 26, 10, 5},
      {27, 28, 17, 6}, {29, 11, 18, 7}, {12, 20, 22, 8}, {23, 24, 19, 21}};
  const int cls = QT[gq >> 2][((gq & 3) + gp) & 3];
  const int bh = (id & 7) + 8 * gp;
  const int b = bh >> 4, h = bh & 15;

  int tile, k, c_lo, c_hi, sbase;
  if (cls < 5)        { tile = cls;
                        c_lo = 0; c_hi = 2 * tile + 1; sbase = -1; }
  else if (cls < 17)  { tile = 5 + ((cls - 5) >> 1); k = (cls - 5) & 1;
                        int half = tile + 1;
                        c_lo = k * half; c_hi = c_lo + half - 1;
                        sbase = (tile - 5) * 2 + k; }
  else                { int d3 = cls - 17; int t3 = d3 / 3; k = d3 - 3 * t3;
                        tile = 11 + t3; int C = 2 * tile + 2;
                        c_lo = (k * C) / 3; c_hi = ((k + 1) * C) / 3 - 1;
                        sbase = 12 + t3 * 3 + k; }
  const bool partial = (sbase >= 0);
  const int qb0 = tile * 128 + wave * 32;

  short8 qf[2][2];
#pragma unroll
  for (int j = 0; j < 2; j++) {
    const u16* qrow = Q + (size_t)(b * NT + qb0 + j * 16 + l15) * NC + h * ND + quad * 8;
    qf[j][0] = *(const short8*)(qrow);
    qf[j][1] = *(const short8*)(qrow + 32);
  }

  const short4v vone = {(short)0x3F80, (short)0x3F80, (short)0x3F80, (short)0x3F80};
  float4v l_acc[2];
  float4v o_acc[2][4];
#pragma unroll
  for (int j = 0; j < 2; j++) {
    l_acc[j] = (float4v){0.f, 0.f, 0.f, 0.f};
#pragma unroll
    for (int dt = 0; dt < 4; dt++) o_acc[j][dt] = (float4v){0.f, 0.f, 0.f, 0.f};
  }

  int kOff[2], vOff[2], ldsOff[2];
#pragma unroll
  for (int ii = 0; ii < 2; ii++) {
    int row = wave * 16 + ii * 8 + r8;
    int gc  = c8 ^ (row & 7);
    kOff[ii]   = row * NC + gc * 8;
    vOff[ii]   = row * NT + gc * 8;
    ldsOff[ii] = (wave * 16 + ii * 8) * 64;
  }
  const u16* Kbase = K  + (size_t)b * NT * NC + h * ND;
  const u16* Vbase = Vt + (size_t)bh * ND * NT;

  auto stage = [&](int ci) {
    const int p = (ci - c_lo) & 1;
    const u16* kc = Kbase + (size_t)ci * (64 * NC);
    const u16* vc = Vbase + ci * 64;
#pragma unroll
    for (int ii = 0; ii < 2; ii++) {
      gld_lds16(kc + kOff[ii], Kc[p] + ldsOff[ii]);
      gld_lds16(vc + vOff[ii], Vc[p] + ldsOff[ii]);
    }
  };

  stage(c_lo);
  for (int i = c_lo; i <= c_hi; i++) {
    const int p = (i - c_lo) & 1;
    WB0;                            // own stage(i) drained, then barrier
    if (i < c_hi) stage(i + 1);     // into p^1: its readers passed the barrier
    // fully-masked tile for this wave: all q-rows < all kv -> P == 0.
    if (i * 64 > qb0 + 31) continue;
    const u16* Ks = Kc[p];
    const u16* Vs = Vc[p];
    const bool anymask = (i * 64 + 63) > qb0;   // wave-uniform diag peel
    __builtin_amdgcn_s_setprio(1);

    // per (j,sub): QK^T -> exp2 -> pack -> PV. Independent chains (no running max).
    short4v pf[2][4];
#pragma unroll
    for (int sub = 0; sub < 4; sub++) {
      float4v a0 = (float4v){0.f, 0.f, 0.f, 0.f};
      float4v a1 = (float4v){0.f, 0.f, 0.f, 0.f};
#pragma unroll
      for (int kk = 0; kk < 2; kk++) {
        int row = sub * 16 + l15;
        int ch  = (kk * 4 + quad) ^ (row & 7);
        short8 kf = *(const short8*)(Ks + row * 64 + ch * 8);
        a0 = __builtin_amdgcn_mfma_f32_16x16x32_bf16(kf, qf[0][kk], a0, 0, 0, 0);
        a1 = __builtin_amdgcn_mfma_f32_16x16x32_bf16(kf, qf[1][kk], a1, 0, 0, 0);
      }
      if (!anymask) {
        // fast path: strictly below diagonal, no element masked
#pragma unroll
        for (int j = 0; j < 2; j++) {
          const float4v& a = (j == 0) ? a0 : a1;
          pf[j][sub] = pack4bf(EXP2(a[0]), EXP2(a[1]), EXP2(a[2]), EXP2(a[3]));
        }
      } else {
#pragma unroll
        for (int j = 0; j < 2; j++) {
          const float4v& a = (j == 0) ? a0 : a1;
          const bool mj = (i * 64 + 63) > (qb0 + j * 16);   // wave-uniform per-j
          const int qg = qb0 + j * 16 + l15;
          float pv[4];
#pragma unroll
          for (int r = 0; r < 4; r++) {
            float pp = EXP2(a[r]);
            if (mj) {
              int sg = i * 64 + sub * 16 + quad * 4 + r;
              if (sg > qg) pp = 0.f;
            }
            pv[r] = pp;
          }
          pf[j][sub] = pack4bf(pv[0], pv[1], pv[2], pv[3]);
        }
      }
    }

    // l on the MFMA pipe: ones^T * P^T accumulates row sums (idle-pipe work)
#pragma unroll
    for (int j = 0; j < 2; j++) {
      l_acc[j] = MFMA16(vone, pf[j][0], l_acc[j]);
      l_acc[j] = MFMA16(vone, pf[j][1], l_acc[j]);
      l_acc[j] = MFMA16(vone, pf[j][2], l_acc[j]);
      l_acc[j] = MFMA16(vone, pf[j][3], l_acc[j]);
    }

    // O^T += V^T * P^T : vf = 2 b128/dt (permuted layout), shared by both subtiles
#pragma unroll
    for (int dt = 0; dt < 4; dt++) {
      int row = dt * 16 + l15;
      int swz = row & 7;
      short8 vA = *(const short8*)(Vs + row * 64 + ((2 * quad)     ^ swz) * 8); // subs 0,1
      short8 vB = *(const short8*)(Vs + row * 64 + ((2 * quad + 1) ^ swz) * 8); // subs 2,3
      short4v vA0 = __builtin_shufflevector(vA, vA, 0, 1, 2, 3);
      short4v vA1 = __builtin_shufflevector(vA, vA, 4, 5, 6, 7);
      short4v vB0 = __builtin_shufflevector(vB, vB, 0, 1, 2, 3);
      short4v vB1 = __builtin_shufflevector(vB, vB, 4, 5, 6, 7);
#pragma unroll
      for (int j = 0; j < 2; j++) {
        o_acc[j][dt] = MFMA16(vA0, pf[j][0], o_acc[j][dt]);
        o_acc[j][dt] = MFMA16(vA1, pf[j][1], o_acc[j][dt]);
        o_acc[j][dt] = MFMA16(vB0, pf[j][2], o_acc[j][dt]);
        o_acc[j][dt] = MFMA16(vB1, pf[j][3], o_acc[j][dt]);
      }
    }
    __builtin_amdgcn_s_setprio(0);
  }

  // l_tot replicated in every l_acc register (rows of ones^T*P^T are identical)
  float l_tot[2] = {l_acc[0][0], l_acc[1][0]};

  if (!partial) {
#pragma unroll
    for (int j = 0; j < 2; j++) {
      float inv_l = 1.f / l_tot[j];
      const size_t orow = (size_t)(b * NT + qb0 + j * 16 + l15) * NC + h * ND;
#pragma unroll
      for (int dt = 0; dt < 4; dt++)
        *(short4v*)(O + orow + dt * 16 + quad * 4) =
            pack4bf(o_acc[j][dt][0] * inv_l, o_acc[j][dt][1] * inv_l,
                    o_acc[j][dt][2] * inv_l, o_acc[j][dt][3] * inv_l);
    }
  } else {
    const int slab = bh * 27 + sbase;
    u16* ob = Opart + (size_t)slab * 8192;
#pragma unroll
    for (int j = 0; j < 2; j++) {
      const int row = wave * 32 + j * 16 + l15;
#pragma unroll
      for (int dt = 0; dt < 4; dt++)
        *(short4v*)(ob + row * 64 + dt * 16 + quad * 4) =
            pack4bf(o_acc[j][dt][0], o_acc[j][dt][1],
                    o_acc[j][dt][2], o_acc[j][dt][3]);   // unnormalized partial
      if (quad == 0)
        Lpart[slab * 128 + row] = l_tot[j];
    }
  }
}

// ---------------- combine split partials (linear: fixed softmax base) ----------------
// tiles 5..10: 2 segments; tiles 11..15: 3 segments. O = sum(O_seg) / sum(l_seg).
__global__ __launch_bounds__(256) void combine(
    const u16* __restrict__ Opart, const float* __restrict__ Lp, u16* __restrict__ O) {
  int idx  = blockIdx.x * 256 + threadIdx.x;   // 0 .. 352*1024-1
  int tIdx = idx >> 10;                        // (bh, tile-5) pair, 0..351
  int rem8 = idx & 1023;                       // 16B chunk within the 128x64 slab
  int row  = rem8 >> 3, d0 = (rem8 & 7) * 8;
  int bh   = tIdx / 11;
  int tt   = tIdx - bh * 11;                   // 0..10 -> tile 5..15
  int tile = 5 + tt;
  int S, sb;
  if (tile < 11) { S = 2; sb = (tile - 5) * 2; }
  else           { S = 3; sb = 12 + (tile - 11) * 3; }
  int slab0 = bh * 27 + sb;
  float osum[8] = {0.f, 0.f, 0.f, 0.f, 0.f, 0.f, 0.f, 0.f};
  float lsum = 0.f;
  for (int s = 0; s < S; s++) {
    short8 v = *(const short8*)(Opart + (size_t)(slab0 + s) * 8192 + rem8 * 8);
#pragma unroll
    for (int e = 0; e < 8; e++) osum[e] += bf2f((u16)v[e]);
    lsum += Lp[(slab0 + s) * 128 + row];
  }
  float inv = 1.f / lsum;
  short8 o;
#pragma unroll
  for (int e = 0; e < 8; e++) o[e] = (short)f2bf(osum[e] * inv);
  int b = bh >> 4, h = bh & 15;
  int t = tile * 128 + row;
  *(short8*)(O + (size_t)(b * NT + t) * NC + h * ND + d0) = o;
}

// ---------------- output projection: 64x128 tiles, BK=64, single-barrier (r7) --
__global__ __launch_bounds__(256, 2) void out_gemm(
    const u16* __restrict__ Ob, const u16* __restrict__ wpb,
    const float* __restrict__ bp, float* __restrict__ out) {
  __shared__ u16 Sa[2][64 * 64];    // 16 KB
  __shared__ u16 Sb[2][128 * 64];   // 32 KB
  const int n0 = blockIdx.x * 128;
  const int m0 = blockIdx.y * 64;
  const int tid = threadIdx.x, wave = tid >> 6, lane = tid & 63;
  const int quad = lane >> 4, l15 = lane & 15;
  const int wm = wave >> 1, wn = wave & 1;

  const u16* A_tile = Ob  + (size_t)m0 * NC;
  const u16* W_tile = wpb + (size_t)n0 * NC;

  const int srow = (lane >> 3);
  const int sgc  = (lane & 7) ^ srow;
  int sOff[4], sLds[4];
#pragma unroll
  for (int ii = 0; ii < 4; ii++) {
    int row_l = ii * 32 + wave * 8 + srow;
    sOff[ii] = row_l * NC + sgc * 8;
    sLds[ii] = (ii * 32 + wave * 8) * 64;
  }

  float4v acc[2][4];
#pragma unroll
  for (int i = 0; i < 2; i++)
#pragma unroll
    for (int j = 0; j < 4; j++) acc[i][j] = (float4v){0.f, 0.f, 0.f, 0.f};

  auto stage = [&](int ki, int p) {
    const u16* a = A_tile + ki * 64;
    const u16* w = W_tile + ki * 64;
#pragma unroll
    for (int ii = 0; ii < 2; ii++)
      gld_lds16(a + sOff[ii], Sa[p] + sLds[ii]);
#pragma unroll
    for (int ii = 0; ii < 4; ii++)
      gld_lds16(w + sOff[ii], Sb[p] + sLds[ii]);
  };

  stage(0, 0);
  for (int ki = 0; ki < 16; ki++) {
    const int p = ki & 1;
    WB0;
    if (ki < 15) stage(ki + 1, p ^ 1);
#pragma unroll
    for (int kk = 0; kk < 2; kk++) {
      short8 af[2], bf[4];
#pragma unroll
      for (int mt = 0; mt < 2; mt++) {
        int row = wm * 32 + mt * 16 + l15;
        int e   = (kk * 4 + quad) ^ (row & 7);
        af[mt] = *(const short8*)(Sa[p] + row * 64 + e * 8);
      }
#pragma unroll
      for (int nt = 0; nt < 4; nt++) {
        int row = wn * 64 + nt * 16 + l15;
        int e   = (kk * 4 + quad) ^ (row & 7);
        bf[nt] = *(const short8*)(Sb[p] + row * 64 + e * 8);
      }
#pragma unroll
      for (int mt = 0; mt < 2; mt++)
#pragma unroll
        for (int nt = 0; nt < 4; nt++)
          acc[mt][nt] = __builtin_amdgcn_mfma_f32_16x16x32_bf16(af[mt], bf[nt], acc[mt][nt], 0, 0, 0);
    }
  }

#pragma unroll
  for (int nt = 0; nt < 4; nt++) {
    int col = n0 + wn * 64 + nt * 16 + l15;
    float bval = bp[col];
#pragma unroll
    for (int mt = 0; mt < 2; mt++) {
      int rowb = m0 + wm * 32 + mt * 16 + quad * 4;
#pragma unroll
      for (int r = 0; r < 4; r++)
        out[(rowb + r) * NC + col] = acc[mt][nt][r] + bval;
    }
  }
}

extern "C" void kernel_launch(void* const* d_in, const int* in_sizes, int n_in,
                              void* d_out, int out_size, void* d_ws, size_t ws_size,
                              hipStream_t stream) {
  // setup_inputs order: x, Wk, bk, Wq, bq, Wv, bv, Wp, bp
  const float* x  = (const float*)d_in[0];
  const float* Wk = (const float*)d_in[1];
  const float* bk = (const float*)d_in[2];
  const float* Wq = (const float*)d_in[3];
  const float* bq = (const float*)d_in[4];
  const float* Wv = (const float*)d_in[5];
  const float* bv = (const float*)d_in[6];
  const float* Wp = (const float*)d_in[7];
  const float* bp = (const float*)d_in[8];
  float* out = (float*)d_out;

  uint8_t* ws = (uint8_t*)d_ws;
  const size_t MB = 1u << 20;
  // layout: xb[0,8) wk[8,10) wq[10,12) wv[12,14) wp[14,16) — xb/wk/wq/wv die after
  // qkv. Opart reuses [0,13.5): 27 slabs x 32 bh x 16 KB = 13.5 MB. Lpart at
  // [13.5,~13.92) -- inside dead-wv but written only by attn AFTER cast (stream
  // order), so no race. wpb [14,16) stays live for out_gemm.
  u16* xb    = (u16*)(ws + 0 * MB);
  u16* wkb   = (u16*)(ws + 8 * MB);
  u16* wqb   = (u16*)(ws + 10 * MB);
  u16* wvb   = (u16*)(ws + 12 * MB);
  u16* wpb   = (u16*)(ws + 14 * MB);
  u16* Qb    = (u16*)(ws + 16 * MB);
  u16* Kb    = (u16*)(ws + 24 * MB);
  u16* Vtb   = (u16*)(ws + 32 * MB);   // [B,H,D,T'] (s-permuted in 64-chunks)
  u16* Ob    = (u16*)(ws + 40 * MB);   // attention output
  u16* Opart = (u16*)(ws + 0 * MB);    // 864 slabs * 16 KB = 13.5 MB
  float* Lpart = (float*)(ws + 13 * MB + 512 * 1024);   // 864*128*4 = 442 KB

  cast_all<<<8192, 256, 0, stream>>>(x, Wk, Wq, Wv, Wp, xb, wkb, wqb, wvb, wpb);
  qkv_gemm<<<1536, 256, 0, stream>>>(xb, wqb, wkb, wvb, bq, bk, bv, Qb, Kb, Vtb);
  attn<<<1024, 256, 0, stream>>>(Qb, Kb, Vtb, Ob, Opart, Lpart);
  combine<<<1408, 256, 0, stream>>>(Opart, Lpart, Ob);
  out_gemm<<<dim3(8, 64), 256, 0, stream>>>(Ob, wpb, bp, out);
}

// Round 12
// 173.244 us; speedup vs baseline: 1.0239x; 1.0239x over previous
//
#include <hip/hip_runtime.h>
#include <stdint.h>

typedef unsigned short u16;
typedef __attribute__((ext_vector_type(8))) short short8;   // 8 bf16 (4 VGPRs) MFMA A/B frag K=32
typedef __attribute__((ext_vector_type(4))) short short4v;  // 4 bf16 (2 VGPRs) MFMA A/B frag K=16
typedef __attribute__((ext_vector_type(4))) float float4v;  // MFMA C/D frag

#define NB 2
#define NT 2048
#define NC 1024
#define NH 16
#define ND 64
#define NM (NB*NT)   // 4096 rows total

// 16x16x16 bf16 MFMA (2-VGPR operands). Builtin if present, else raw asm.
#if defined(__has_builtin)
#if __has_builtin(__builtin_amdgcn_mfma_f32_16x16x16bf16_1k)
#define MFMA16(a, b, c) __builtin_amdgcn_mfma_f32_16x16x16bf16_1k(a, b, c, 0, 0, 0)
#endif
#endif
#ifndef MFMA16
static __device__ __forceinline__ float4v mfma16_asm(short4v a, short4v b, float4v c) {
  asm volatile("v_mfma_f32_16x16x16_bf16 %0, %1, %2, %0" : "+v"(c) : "v"(a), "v"(b));
  return c;
}
#define MFMA16(a, b, c) mfma16_asm(a, b, c)
#endif

// fast exp2: bare v_exp_f32 (ocml exp2f adds denorm-range fixup we don't need:
// denormal exp2 tails contribute nothing to softmax sums).
#if defined(__has_builtin)
#if __has_builtin(__builtin_amdgcn_exp2f)
#define EXP2(x) __builtin_amdgcn_exp2f(x)
#endif
#endif
#ifndef EXP2
extern "C" __device__ float __ocml_native_exp2_f32(float);
#define EXP2(x) __ocml_native_exp2_f32(x)
#endif

// SINGLE-BARRIER pipelined loop idiom:
//   [waitcnt vmcnt(0) -> own stage(k) landed] [s_barrier -> ALL waves' stage(k)
//   landed AND all readers of buffer p^1 are past iter k-1] [stage(k+1) into p^1]
//   [compute on p].  BK=64 makes the compute phase (~32 MFMA/wave) longer than
//   HBM latency, so the next WB0 finds the loads already landed.
// Session lessons encoded here:
//  r9:  device-scope __threadfence per block ~0.2us cross-XCD L2 writeback;
//       864 blocks = +165us. Launch boundaries (~5us) are CHEAPER. Keep combine
//       as a separate kernel.
//  r10/r11: shrinking tiles for occupancy/dispatch-evenness regresses -- the
//       per-K-step compute phase is the latency cover; don't halve it.
#define WB0 asm volatile("s_waitcnt vmcnt(0)\n\ts_barrier" ::: "memory")
#define BAR_PLAIN asm volatile("s_barrier" ::: "memory")

// fp32 -> bf16 round-to-nearest-even
__device__ __forceinline__ u16 f2bf(float f) {
  union { float f; uint32_t u; } v; v.f = f;
  uint32_t u = v.u;
  u += 0x7fffu + ((u >> 16) & 1u);
  return (u16)(u >> 16);
}
__device__ __forceinline__ float bf2f(u16 u) {
  union { uint32_t u; float f; } v; v.u = ((uint32_t)u) << 16; return v.f;
}

// pack 4 fp32 -> 4 bf16 (truncation) via 2 v_perm_b32
__device__ __forceinline__ short4v pack4bf(float a, float b, float c, float d) {
  union { uint32_t u[2]; short4v s; } r;
  r.u[0] = __builtin_amdgcn_perm(__float_as_uint(b), __float_as_uint(a), 0x07060302u);
  r.u[1] = __builtin_amdgcn_perm(__float_as_uint(d), __float_as_uint(c), 0x07060302u);
  return r.s;
}

// async global->LDS, 16B per lane; lds dest wave-uniform (lane i -> lds + i*16B)
__device__ __forceinline__ void gld_lds16(const u16* g, u16* lds) {
  __builtin_amdgcn_global_load_lds(
      (const __attribute__((address_space(1))) uint32_t*)g,
      (__attribute__((address_space(3))) uint32_t*)lds,
      16, 0, 0);
}

// ---------------- cast: x, Wk, Wq, Wv, Wp -> bf16 ----------------
__global__ __launch_bounds__(256) void cast_all(
    const float* __restrict__ x,  const float* __restrict__ wk,
    const float* __restrict__ wq, const float* __restrict__ wv,
    const float* __restrict__ wp,
    u16* __restrict__ xb, u16* __restrict__ wkb, u16* __restrict__ wqb,
    u16* __restrict__ wvb, u16* __restrict__ wpb) {
  const int NX = NM * NC / 4;
  const int NW = NC * NC / 4;
  int i = blockIdx.x * 256 + threadIdx.x;
  const float* src; u16* dst; int off;
  if (i < NX)            { src = x;  dst = xb;  off = i; }
  else if (i < NX+NW)    { src = wk; dst = wkb; off = i - NX; }
  else if (i < NX+2*NW)  { src = wq; dst = wqb; off = i - NX - NW; }
  else if (i < NX+3*NW)  { src = wv; dst = wvb; off = i - NX - 2*NW; }
  else if (i < NX+4*NW)  { src = wp; dst = wpb; off = i - NX - 3*NW; }
  else return;
  float4v f = ((const float4v*)src)[off];
  short4v o;
  o.x = (short)f2bf(f.x); o.y = (short)f2bf(f.y);
  o.z = (short)f2bf(f.z); o.w = (short)f2bf(f.w);
  ((short4v*)dst)[off] = o;
}

// ---------------- fused QKV projection + in-kernel V transpose (PIPELINED) ----------
// 1D grid 768. XCD = id%8 owns m-group (4 m-tiles = 1 MB of xb); iterates all
// 8 n-tiles x 3 mats (all W = 6 MB) -> per-XCD footprint ~7 MB.
// BK=64: 16 K-steps, 32 MFMA/wave per step -> compute phase covers HBM latency.
// 64 KB LDS double-buffer, 2 blocks/CU, single barrier per K-step.
__global__ __launch_bounds__(256, 2) void qkv_gemm(
    const u16* __restrict__ xb,
    const u16* __restrict__ wqb, const u16* __restrict__ wkb, const u16* __restrict__ wvb,
    const float* __restrict__ bq, const float* __restrict__ bk, const float* __restrict__ bv,
    u16* __restrict__ Q, u16* __restrict__ K, u16* __restrict__ Vt) {
  __shared__ u16 S[4][128 * 64];     // A0 A1 B0 B1 = 64 KB
  const int id  = blockIdx.x;
  const int mg  = id & 7;            // XCD-owned m-group
  const int mti = mg * 4 + ((id >> 3) & 3);   // m tile 0..31
  const int rr  = id >> 5;           // 0..23
  const int x8  = rr & 7;            // n tile
  const int mat = rr >> 3;           // 0=Q 1=K 2=V
  const int n0  = x8 * 128;
  const int m0  = mti * 128;
  const u16*   W    = (mat == 0) ? wqb : (mat == 1) ? wkb : wvb;
  const float* bias = (mat == 0) ? bq  : (mat == 1) ? bk  : bv;

  const int tid = threadIdx.x, wave = tid >> 6, lane = tid & 63;
  const int quad = lane >> 4, l15 = lane & 15;
  const int wm = wave >> 1, wn = wave & 1;

  const u16* A_tile = xb + (size_t)m0 * NC;
  const u16* W_tile = W  + (size_t)n0 * NC;

  const int srow = (lane >> 3);                 // 0..7 within wave's 8-row group
  const int sgc  = (lane & 7) ^ srow;           // swizzled global chunk
  int sOff[4], sLds[4];
#pragma unroll
  for (int ii = 0; ii < 4; ii++) {
    int row_l = ii * 32 + wave * 8 + srow;
    sOff[ii] = row_l * NC + sgc * 8;
    sLds[ii] = (ii * 32 + wave * 8) * 64;       // wave-uniform LDS base (u16)
  }

  float4v acc[4][4];
#pragma unroll
  for (int i = 0; i < 4; i++)
#pragma unroll
    for (int j = 0; j < 4; j++) acc[i][j] = (float4v){0.f, 0.f, 0.f, 0.f};

  auto stage = [&](int ki, int p) {
    const u16* a = A_tile + ki * 64;
    const u16* w = W_tile + ki * 64;
#pragma unroll
    for (int ii = 0; ii < 4; ii++) {
      gld_lds16(a + sOff[ii], S[p]     + sLds[ii]);
      gld_lds16(w + sOff[ii], S[2 + p] + sLds[ii]);
    }
  };

  stage(0, 0);
  for (int ki = 0; ki < 16; ki++) {
    const int p = ki & 1;
    WB0;                            // own stage(ki) drained, then barrier
    if (ki < 15) stage(ki + 1, p ^ 1);   // overwrite p^1: its readers passed barrier
    const u16* As = S[p];
    const u16* Bs = S[2 + p];
#pragma unroll
    for (int kk = 0; kk < 2; kk++) {
      short8 af[4], bf[4];
#pragma unroll
      for (int mt = 0; mt < 4; mt++) {
        int row = wm * 64 + mt * 16 + l15;
        int e   = (kk * 4 + quad) ^ (row & 7);
        af[mt] = *(const short8*)(As + row * 64 + e * 8);
      }
#pragma unroll
      for (int nt = 0; nt < 4; nt++) {
        int row = wn * 64 + nt * 16 + l15;
        int e   = (kk * 4 + quad) ^ (row & 7);
        bf[nt] = *(const short8*)(Bs + row * 64 + e * 8);
      }
#pragma unroll
      for (int mt = 0; mt < 4; mt++)
#pragma unroll
        for (int nt = 0; nt < 4; nt++)
          acc[mt][nt] = __builtin_amdgcn_mfma_f32_16x16x32_bf16(af[mt], bf[nt], acc[mt][nt], 0, 0, 0);
    }
  }

  if (mat != 2) {
    // Q/K: repack via LDS, then coalesced 16B stores. Bank swizzle: XOR col bits
    // 4..6 with (row>>2)&7 so the 4 quad-rows of one store land in distinct 32B
    // segments.
    u16* dst = (mat == 0) ? Q : K;
    const float osc = (mat == 0) ? 0.18033688f : 1.0f;   // fold 0.125*log2(e) into Q
    BAR_PLAIN;                       // all waves done reading S before reuse
    u16* tile = (u16*)S;             // [128 rows][128 cols] u16, swizzled
#pragma unroll
    for (int nt = 0; nt < 4; nt++) {
      int col = wn * 64 + nt * 16 + l15;
      float bval = bias[n0 + col];
#pragma unroll
      for (int mt = 0; mt < 4; mt++) {
        int rowb = wm * 64 + mt * 16 + quad * 4;
#pragma unroll
        for (int r = 0; r < 4; r++) {
          int row = rowb + r;
          tile[row * 128 + (col ^ (((row >> 2) & 7) << 4))] =
              f2bf((acc[mt][nt][r] + bval) * osc);
        }
      }
    }
    __syncthreads();
#pragma unroll
    for (int it = 0; it < 8; it++) {
      int idx = it * 256 + tid;      // 0..2047: 128 rows x 16 col-chunks of 16B
      int row = idx >> 4, ck = idx & 15;
      int s = (row >> 2) & 7;
      short8 v = *(const short8*)(tile + row * 128 + ((((ck >> 1) ^ s) << 4) | ((ck & 1) << 3)));
      *(short8*)(dst + (size_t)(m0 + row) * NC + n0 + ck * 8) = v;
    }
  } else {
    // V: transpose + s-permute via LDS.
    BAR_PLAIN;                       // all waves done reading S before reuse
    u16* tile = (u16*)S;
#pragma unroll
    for (int nt = 0; nt < 4; nt++) {
      int c = wn * 64 + nt * 16 + l15;
      float bval = bias[n0 + c];
#pragma unroll
      for (int mt = 0; mt < 4; mt++) {
#pragma unroll
        for (int r = 0; r < 4; r++) {
          int mr  = mt * 4 + r;
          int off = wm * 64 + quad * 16 + mr;          // permuted t position
          int ck  = (off >> 3) ^ (c & 15);
          tile[c * 128 + ck * 8 + (off & 7)] = f2bf(acc[mt][nt][r] + bval);
        }
      }
    }
    __syncthreads();
    const int b  = m0 >> 11, t0 = m0 & 2047;
    const int bh0 = b * NH + (n0 >> 6);
#pragma unroll
    for (int it = 0; it < 8; it++) {
      int idx = it * 256 + tid;      // 0..2047 chunks of 16 B
      int c = idx >> 4, ck = idx & 15;
      short8 v = *(const short8*)(tile + c * 128 + ((ck ^ (c & 15)) * 8));
      *(short8*)(Vt + ((size_t)(bh0 + (c >> 6)) * ND + (c & 63)) * NT + t0 + ck * 8) = v;
    }
  }
}

// ---------------- flash attention (causal), fixed-max softmax, 32 classes/bh ----
// 4 waves x 32 q-rows; single barrier per kv-tile; l on MFMA pipe; setprio(1);
// fully-masked-tile skip + diagonal peel (r6 structure, best measured).
__global__ __launch_bounds__(256, 4) void attn(
    const u16* __restrict__ Q, const u16* __restrict__ K,
    const u16* __restrict__ Vt, u16* __restrict__ O,
    u16* __restrict__ Opart, float* __restrict__ Lpart) {
  __shared__ u16 Kc[2][64 * 64];   // [s][d] swizzled
  __shared__ u16 Vc[2][64 * 64];   // [d][pos(s)] swizzled

  const int tid = threadIdx.x, wave = tid >> 6, lane = tid & 63;
  const int quad = lane >> 4, l15 = lane & 15;
  const int c8 = lane & 7, r8 = lane >> 3;
  const int id = blockIdx.x;
  const int gq = (id >> 3) & 31;   // class-group (same for a CU's 4 blocks)
  const int gp = id >> 8;          // pass 0..3
  static const uint8_t QT[8][4] = {
      {15, 16, 4, 0}, {30, 31, 3, 1}, {13, 14, 9, 2}, {25, 26, 10, 5},
      {27, 28, 17, 6}, {29, 11, 18, 7}, {12, 20, 22, 8}, {23, 24, 19, 21}};
  const int cls = QT[gq >> 2][((gq & 3) + gp) & 3];
  const int bh = (id & 7) + 8 * gp;
  const int b = bh >> 4, h = bh & 15;

  int tile, k, c_lo, c_hi, sbase;
  if (cls < 5)        { tile = cls;
                        c_lo = 0; c_hi = 2 * tile + 1; sbase = -1; }
  else if (cls < 17)  { tile = 5 + ((cls - 5) >> 1); k = (cls - 5) & 1;
                        int half = tile + 1;
                        c_lo = k * half; c_hi = c_lo + half - 1;
                        sbase = (tile - 5) * 2 + k; }
  else                { int d3 = cls - 17; int t3 = d3 / 3; k = d3 - 3 * t3;
                        tile = 11 + t3; int C = 2 * tile + 2;
                        c_lo = (k * C) / 3; c_hi = ((k + 1) * C) / 3 - 1;
                        sbase = 12 + t3 * 3 + k; }
  const bool partial = (sbase >= 0);
  const int qb0 = tile * 128 + wave * 32;

  short8 qf[2][2];
#pragma unroll
  for (int j = 0; j < 2; j++) {
    const u16* qrow = Q + (size_t)(b * NT + qb0 + j * 16 + l15) * NC + h * ND + quad * 8;
    qf[j][0] = *(const short8*)(qrow);
    qf[j][1] = *(const short8*)(qrow + 32);
  }

  const short4v vone = {(short)0x3F80, (short)0x3F80, (short)0x3F80, (short)0x3F80};
  float4v l_acc[2];
  float4v o_acc[2][4];
#pragma unroll
  for (int j = 0; j < 2; j++) {
    l_acc[j] = (float4v){0.f, 0.f, 0.f, 0.f};
#pragma unroll
    for (int dt = 0; dt < 4; dt++) o_acc[j][dt] = (float4v){0.f, 0.f, 0.f, 0.f};
  }

  int kOff[2], vOff[2], ldsOff[2];
#pragma unroll
  for (int ii = 0; ii < 2; ii++) {
    int row = wave * 16 + ii * 8 + r8;
    int gc  = c8 ^ (row & 7);
    kOff[ii]   = row * NC + gc * 8;
    vOff[ii]   = row * NT + gc * 8;
    ldsOff[ii] = (wave * 16 + ii * 8) * 64;
  }
  const u16* Kbase = K  + (size_t)b * NT * NC + h * ND;
  const u16* Vbase = Vt + (size_t)bh * ND * NT;

  auto stage = [&](int ci) {
    const int p = (ci - c_lo) & 1;
    const u16* kc = Kbase + (size_t)ci * (64 * NC);
    const u16* vc = Vbase + ci * 64;
#pragma unroll
    for (int ii = 0; ii < 2; ii++) {
      gld_lds16(kc + kOff[ii], Kc[p] + ldsOff[ii]);
      gld_lds16(vc + vOff[ii], Vc[p] + ldsOff[ii]);
    }
  };

  stage(c_lo);
  for (int i = c_lo; i <= c_hi; i++) {
    const int p = (i - c_lo) & 1;
    WB0;                            // own stage(i) drained, then barrier
    if (i < c_hi) stage(i + 1);     // into p^1: its readers passed the barrier
    // fully-masked tile for this wave: all q-rows < all kv -> P == 0.
    if (i * 64 > qb0 + 31) continue;
    const u16* Ks = Kc[p];
    const u16* Vs = Vc[p];
    const bool anymask = (i * 64 + 63) > qb0;   // wave-uniform diag peel
    __builtin_amdgcn_s_setprio(1);

    // per (j,sub): QK^T -> exp2 -> pack -> PV. Independent chains (no running max).
    short4v pf[2][4];
#pragma unroll
    for (int sub = 0; sub < 4; sub++) {
      float4v a0 = (float4v){0.f, 0.f, 0.f, 0.f};
      float4v a1 = (float4v){0.f, 0.f, 0.f, 0.f};
#pragma unroll
      for (int kk = 0; kk < 2; kk++) {
        int row = sub * 16 + l15;
        int ch  = (kk * 4 + quad) ^ (row & 7);
        short8 kf = *(const short8*)(Ks + row * 64 + ch * 8);
        a0 = __builtin_amdgcn_mfma_f32_16x16x32_bf16(kf, qf[0][kk], a0, 0, 0, 0);
        a1 = __builtin_amdgcn_mfma_f32_16x16x32_bf16(kf, qf[1][kk], a1, 0, 0, 0);
      }
      if (!anymask) {
        // fast path: strictly below diagonal, no element masked
#pragma unroll
        for (int j = 0; j < 2; j++) {
          const float4v& a = (j == 0) ? a0 : a1;
          pf[j][sub] = pack4bf(EXP2(a[0]), EXP2(a[1]), EXP2(a[2]), EXP2(a[3]));
        }
      } else {
#pragma unroll
        for (int j = 0; j < 2; j++) {
          const float4v& a = (j == 0) ? a0 : a1;
          const bool mj = (i * 64 + 63) > (qb0 + j * 16);   // wave-uniform per-j
          const int qg = qb0 + j * 16 + l15;
          float pv[4];
#pragma unroll
          for (int r = 0; r < 4; r++) {
            float pp = EXP2(a[r]);
            if (mj) {
              int sg = i * 64 + sub * 16 + quad * 4 + r;
              if (sg > qg) pp = 0.f;
            }
            pv[r] = pp;
          }
          pf[j][sub] = pack4bf(pv[0], pv[1], pv[2], pv[3]);
        }
      }
    }

    // l on the MFMA pipe: ones^T * P^T accumulates row sums (idle-pipe work)
#pragma unroll
    for (int j = 0; j < 2; j++) {
      l_acc[j] = MFMA16(vone, pf[j][0], l_acc[j]);
      l_acc[j] = MFMA16(vone, pf[j][1], l_acc[j]);
      l_acc[j] = MFMA16(vone, pf[j][2], l_acc[j]);
      l_acc[j] = MFMA16(vone, pf[j][3], l_acc[j]);
    }

    // O^T += V^T * P^T : vf = 2 b128/dt (permuted layout), shared by both subtiles
#pragma unroll
    for (int dt = 0; dt < 4; dt++) {
      int row = dt * 16 + l15;
      int swz = row & 7;
      short8 vA = *(const short8*)(Vs + row * 64 + ((2 * quad)     ^ swz) * 8); // subs 0,1
      short8 vB = *(const short8*)(Vs + row * 64 + ((2 * quad + 1) ^ swz) * 8); // subs 2,3
      short4v vA0 = __builtin_shufflevector(vA, vA, 0, 1, 2, 3);
      short4v vA1 = __builtin_shufflevector(vA, vA, 4, 5, 6, 7);
      short4v vB0 = __builtin_shufflevector(vB, vB, 0, 1, 2, 3);
      short4v vB1 = __builtin_shufflevector(vB, vB, 4, 5, 6, 7);
#pragma unroll
      for (int j = 0; j < 2; j++) {
        o_acc[j][dt] = MFMA16(vA0, pf[j][0], o_acc[j][dt]);
        o_acc[j][dt] = MFMA16(vA1, pf[j][1], o_acc[j][dt]);
        o_acc[j][dt] = MFMA16(vB0, pf[j][2], o_acc[j][dt]);
        o_acc[j][dt] = MFMA16(vB1, pf[j][3], o_acc[j][dt]);
      }
    }
    __builtin_amdgcn_s_setprio(0);
  }

  // l_tot replicated in every l_acc register (rows of ones^T*P^T are identical)
  float l_tot[2] = {l_acc[0][0], l_acc[1][0]};

  if (!partial) {
#pragma unroll
    for (int j = 0; j < 2; j++) {
      float inv_l = 1.f / l_tot[j];
      const size_t orow = (size_t)(b * NT + qb0 + j * 16 + l15) * NC + h * ND;
#pragma unroll
      for (int dt = 0; dt < 4; dt++)
        *(short4v*)(O + orow + dt * 16 + quad * 4) =
            pack4bf(o_acc[j][dt][0] * inv_l, o_acc[j][dt][1] * inv_l,
                    o_acc[j][dt][2] * inv_l, o_acc[j][dt][3] * inv_l);
    }
  } else {
    const int slab = bh * 27 + sbase;
    u16* ob = Opart + (size_t)slab * 8192;
#pragma unroll
    for (int j = 0; j < 2; j++) {
      const int row = wave * 32 + j * 16 + l15;
#pragma unroll
      for (int dt = 0; dt < 4; dt++)
        *(short4v*)(ob + row * 64 + dt * 16 + quad * 4) =
            pack4bf(o_acc[j][dt][0], o_acc[j][dt][1],
                    o_acc[j][dt][2], o_acc[j][dt][3]);   // unnormalized partial
      if (quad == 0)
        Lpart[slab * 128 + row] = l_tot[j];
    }
  }
}

// ---------------- combine split partials (linear: fixed softmax base) ----------------
// tiles 5..10: 2 segments; tiles 11..15: 3 segments. O = sum(O_seg) / sum(l_seg).
// Vectorized x8: each thread handles one 16B chunk (8 bf16 of one row).
__global__ __launch_bounds__(256) void combine(
    const u16* __restrict__ Opart, const float* __restrict__ Lp, u16* __restrict__ O) {
  int idx  = blockIdx.x * 256 + threadIdx.x;   // 0 .. 352*1024-1
  int tIdx = idx >> 10;                        // (bh, tile-5) pair, 0..351
  int rem8 = idx & 1023;                       // 16B chunk within the 128x64 slab
  int row  = rem8 >> 3, d0 = (rem8 & 7) * 8;
  int bh   = tIdx / 11;
  int tt   = tIdx - bh * 11;                   // 0..10 -> tile 5..15
  int tile = 5 + tt;
  int S, sb;
  if (tile < 11) { S = 2; sb = (tile - 5) * 2; }
  else           { S = 3; sb = 12 + (tile - 11) * 3; }
  int slab0 = bh * 27 + sb;
  float osum[8] = {0.f, 0.f, 0.f, 0.f, 0.f, 0.f, 0.f, 0.f};
  float lsum = 0.f;
  for (int s = 0; s < S; s++) {
    short8 v = *(const short8*)(Opart + (size_t)(slab0 + s) * 8192 + rem8 * 8);
#pragma unroll
    for (int e = 0; e < 8; e++) osum[e] += bf2f((u16)v[e]);
    lsum += Lp[(slab0 + s) * 128 + row];
  }
  float inv = 1.f / lsum;
  short8 o;
#pragma unroll
  for (int e = 0; e < 8; e++) o[e] = (short)f2bf(osum[e] * inv);
  int b = bh >> 4, h = bh & 15;
  int t = tile * 128 + row;
  *(short8*)(O + (size_t)(b * NT + t) * NC + h * ND + d0) = o;
}

// ---------------- output projection: 64x128 tiles, BK=64, single-barrier ------
__global__ __launch_bounds__(256, 2) void out_gemm(
    const u16* __restrict__ Ob, const u16* __restrict__ wpb,
    const float* __restrict__ bp, float* __restrict__ out) {
  __shared__ u16 Sa[2][64 * 64];    // 16 KB
  __shared__ u16 Sb[2][128 * 64];   // 32 KB
  const int n0 = blockIdx.x * 128;
  const int m0 = blockIdx.y * 64;
  const int tid = threadIdx.x, wave = tid >> 6, lane = tid & 63;
  const int quad = lane >> 4, l15 = lane & 15;
  const int wm = wave >> 1, wn = wave & 1;

  const u16* A_tile = Ob  + (size_t)m0 * NC;
  const u16* W_tile = wpb + (size_t)n0 * NC;

  const int srow = (lane >> 3);
  const int sgc  = (lane & 7) ^ srow;
  int sOff[4], sLds[4];
#pragma unroll
  for (int ii = 0; ii < 4; ii++) {
    int row_l = ii * 32 + wave * 8 + srow;
    sOff[ii] = row_l * NC + sgc * 8;
    sLds[ii] = (ii * 32 + wave * 8) * 64;
  }

  float4v acc[2][4];
#pragma unroll
  for (int i = 0; i < 2; i++)
#pragma unroll
    for (int j = 0; j < 4; j++) acc[i][j] = (float4v){0.f, 0.f, 0.f, 0.f};

  auto stage = [&](int ki, int p) {
    const u16* a = A_tile + ki * 64;
    const u16* w = W_tile + ki * 64;
#pragma unroll
    for (int ii = 0; ii < 2; ii++)
      gld_lds16(a + sOff[ii], Sa[p] + sLds[ii]);
#pragma unroll
    for (int ii = 0; ii < 4; ii++)
      gld_lds16(w + sOff[ii], Sb[p] + sLds[ii]);
  };

  stage(0, 0);
  for (int ki = 0; ki < 16; ki++) {
    const int p = ki & 1;
    WB0;
    if (ki < 15) stage(ki + 1, p ^ 1);
#pragma unroll
    for (int kk = 0; kk < 2; kk++) {
      short8 af[2], bf[4];
#pragma unroll
      for (int mt = 0; mt < 2; mt++) {
        int row = wm * 32 + mt * 16 + l15;
        int e   = (kk * 4 + quad) ^ (row & 7);
        af[mt] = *(const short8*)(Sa[p] + row * 64 + e * 8);
      }
#pragma unroll
      for (int nt = 0; nt < 4; nt++) {
        int row = wn * 64 + nt * 16 + l15;
        int e   = (kk * 4 + quad) ^ (row & 7);
        bf[nt] = *(const short8*)(Sb[p] + row * 64 + e * 8);
      }
#pragma unroll
      for (int mt = 0; mt < 2; mt++)
#pragma unroll
        for (int nt = 0; nt < 4; nt++)
          acc[mt][nt] = __builtin_amdgcn_mfma_f32_16x16x32_bf16(af[mt], bf[nt], acc[mt][nt], 0, 0, 0);
    }
  }

#pragma unroll
  for (int nt = 0; nt < 4; nt++) {
    int col = n0 + wn * 64 + nt * 16 + l15;
    float bval = bp[col];
#pragma unroll
    for (int mt = 0; mt < 2; mt++) {
      int rowb = m0 + wm * 32 + mt * 16 + quad * 4;
#pragma unroll
      for (int r = 0; r < 4; r++)
        out[(rowb + r) * NC + col] = acc[mt][nt][r] + bval;
    }
  }
}

extern "C" void kernel_launch(void* const* d_in, const int* in_sizes, int n_in,
                              void* d_out, int out_size, void* d_ws, size_t ws_size,
                              hipStream_t stream) {
  // setup_inputs order: x, Wk, bk, Wq, bq, Wv, bv, Wp, bp
  const float* x  = (const float*)d_in[0];
  const float* Wk = (const float*)d_in[1];
  const float* bk = (const float*)d_in[2];
  const float* Wq = (const float*)d_in[3];
  const float* bq = (const float*)d_in[4];
  const float* Wv = (const float*)d_in[5];
  const float* bv = (const float*)d_in[6];
  const float* Wp = (const float*)d_in[7];
  const float* bp = (const float*)d_in[8];
  float* out = (float*)d_out;

  uint8_t* ws = (uint8_t*)d_ws;
  const size_t MB = 1u << 20;
  // layout: xb[0,8) wk[8,10) wq[10,12) wv[12,14) wp[14,16) — xb/wk/wq/wv die after
  // qkv. Opart reuses [0,13.5): 27 slabs x 32 bh x 16 KB = 13.5 MB. Lpart at
  // [13.5,~13.92) -- inside dead-wv but written only by attn AFTER cast (stream
  // order), so no race. wpb [14,16) stays live for out_gemm.
  u16* xb    = (u16*)(ws + 0 * MB);
  u16* wkb   = (u16*)(ws + 8 * MB);
  u16* wqb   = (u16*)(ws + 10 * MB);
  u16* wvb   = (u16*)(ws + 12 * MB);
  u16* wpb   = (u16*)(ws + 14 * MB);
  u16* Qb    = (u16*)(ws + 16 * MB);
  u16* Kb    = (u16*)(ws + 24 * MB);
  u16* Vtb   = (u16*)(ws + 32 * MB);   // [B,H,D,T'] (s-permuted in 64-chunks)
  u16* Ob    = (u16*)(ws + 40 * MB);   // attention output
  u16* Opart = (u16*)(ws + 0 * MB);    // 864 slabs * 16 KB = 13.5 MB
  float* Lpart = (float*)(ws + 13 * MB + 512 * 1024);   // 864*128*4 = 442 KB

  cast_all<<<8192, 256, 0, stream>>>(x, Wk, Wq, Wv, Wp, xb, wkb, wqb, wvb, wpb);
  qkv_gemm<<<768, 256, 0, stream>>>(xb, wqb, wkb, wvb, bq, bk, bv, Qb, Kb, Vtb);
  attn<<<1024, 256, 0, stream>>>(Qb, Kb, Vtb, Ob, Opart, Lpart);
  combine<<<1408, 256, 0, stream>>>(Opart, Lpart, Ob);
  out_gemm<<<dim3(8, 64), 256, 0, stream>>>(Ob, wpb, bp, out);
}

// Round 14
// 169.942 us; speedup vs baseline: 1.0438x; 1.0194x over previous
//
#include <hip/hip_runtime.h>
#include <stdint.h>

typedef unsigned short u16;
typedef __attribute__((ext_vector_type(8))) short short8;   // 8 bf16 (4 VGPRs) MFMA A/B frag K=32
typedef __attribute__((ext_vector_type(4))) short short4v;  // 4 bf16 (2 VGPRs) MFMA A/B frag K=16
typedef __attribute__((ext_vector_type(4))) float float4v;  // MFMA C/D frag

#define NB 2
#define NT 2048
#define NC 1024
#define NH 16
#define ND 64
#define NM (NB*NT)   // 4096 rows total

// 16x16x16 bf16 MFMA (2-VGPR operands). Builtin if present, else raw asm.
#if defined(__has_builtin)
#if __has_builtin(__builtin_amdgcn_mfma_f32_16x16x16bf16_1k)
#define MFMA16(a, b, c) __builtin_amdgcn_mfma_f32_16x16x16bf16_1k(a, b, c, 0, 0, 0)
#endif
#endif
#ifndef MFMA16
static __device__ __forceinline__ float4v mfma16_asm(short4v a, short4v b, float4v c) {
  asm volatile("v_mfma_f32_16x16x16_bf16 %0, %1, %2, %0" : "+v"(c) : "v"(a), "v"(b));
  return c;
}
#define MFMA16(a, b, c) mfma16_asm(a, b, c)
#endif

// fast exp2: bare v_exp_f32 (ocml exp2f adds denorm-range fixup we don't need:
// denormal exp2 tails contribute nothing to softmax sums).
#if defined(__has_builtin)
#if __has_builtin(__builtin_amdgcn_exp2f)
#define EXP2(x) __builtin_amdgcn_exp2f(x)
#endif
#endif
#ifndef EXP2
extern "C" __device__ float __ocml_native_exp2_f32(float);
#define EXP2(x) __ocml_native_exp2_f32(x)
#endif

// SINGLE-BARRIER pipelined loop idiom:
//   [waitcnt vmcnt(0) -> own stage(k) landed] [s_barrier -> ALL waves' stage(k)
//   landed AND all readers of buffer p^1 are past iter k-1] [stage(k+1) into p^1]
//   [compute on p].  BK=64 makes the compute phase (~32 MFMA/wave) longer than
//   HBM latency, so the next WB0 finds the loads already landed.
// Session lessons encoded here:
//  r9:  device-scope __threadfence per block ~0.2us cross-XCD L2 writeback;
//       864 blocks = +165us. Launch boundaries (~5us) are CHEAPER. Keep
//       producer/consumer stages as separate kernels.
//  r10/r11: shrinking GEMM tiles for occupancy/dispatch-evenness regresses --
//       the per-K-step compute phase is the latency cover; don't halve it at
//       2 blocks/CU. (attn differs: its latency hiding comes from 16 waves/CU
//       of cross-block TLP -- r5/r6 evidence.)
#define WB0 asm volatile("s_waitcnt vmcnt(0)\n\ts_barrier" ::: "memory")
#define BAR_PLAIN asm volatile("s_barrier" ::: "memory")

// fp32 -> bf16 round-to-nearest-even
__device__ __forceinline__ u16 f2bf(float f) {
  union { float f; uint32_t u; } v; v.f = f;
  uint32_t u = v.u;
  u += 0x7fffu + ((u >> 16) & 1u);
  return (u16)(u >> 16);
}
__device__ __forceinline__ float bf2f(u16 u) {
  union { uint32_t u; float f; } v; v.u = ((uint32_t)u) << 16; return v.f;
}

// pack 4 fp32 -> 4 bf16 (truncation) via 2 v_perm_b32
__device__ __forceinline__ short4v pack4bf(float a, float b, float c, float d) {
  union { uint32_t u[2]; short4v s; } r;
  r.u[0] = __builtin_amdgcn_perm(__float_as_uint(b), __float_as_uint(a), 0x07060302u);
  r.u[1] = __builtin_amdgcn_perm(__float_as_uint(d), __float_as_uint(c), 0x07060302u);
  return r.s;
}

// async global->LDS, 16B per lane; lds dest wave-uniform (lane i -> lds + i*16B)
__device__ __forceinline__ void gld_lds16(const u16* g, u16* lds) {
  __builtin_amdgcn_global_load_lds(
      (const __attribute__((address_space(1))) uint32_t*)g,
      (__attribute__((address_space(3))) uint32_t*)lds,
      16, 0, 0);
}

// ---------------- cast: x, Wk, Wq, Wv, Wp -> bf16 ----------------
__global__ __launch_bounds__(256) void cast_all(
    const float* __restrict__ x,  const float* __restrict__ wk,
    const float* __restrict__ wq, const float* __restrict__ wv,
    const float* __restrict__ wp,
    u16* __restrict__ xb, u16* __restrict__ wkb, u16* __restrict__ wqb,
    u16* __restrict__ wvb, u16* __restrict__ wpb) {
  const int NX = NM * NC / 4;
  const int NW = NC * NC / 4;
  int i = blockIdx.x * 256 + threadIdx.x;
  const float* src; u16* dst; int off;
  if (i < NX)            { src = x;  dst = xb;  off = i; }
  else if (i < NX+NW)    { src = wk; dst = wkb; off = i - NX; }
  else if (i < NX+2*NW)  { src = wq; dst = wqb; off = i - NX - NW; }
  else if (i < NX+3*NW)  { src = wv; dst = wvb; off = i - NX - 2*NW; }
  else if (i < NX+4*NW)  { src = wp; dst = wpb; off = i - NX - 3*NW; }
  else return;
  float4v f = ((const float4v*)src)[off];
  short4v o;
  o.x = (short)f2bf(f.x); o.y = (short)f2bf(f.y);
  o.z = (short)f2bf(f.z); o.w = (short)f2bf(f.w);
  ((short4v*)dst)[off] = o;
}

// ---------------- fused QKV projection + in-kernel V transpose (PIPELINED) ----------
// 1D grid 768. XCD = id%8 owns m-group (4 m-tiles = 1 MB of xb); iterates all
// 8 n-tiles x 3 mats (all W = 6 MB) -> per-XCD footprint ~7 MB.
// BK=64: 16 K-steps, 32 MFMA/wave per step -> compute phase covers HBM latency.
// 64 KB LDS double-buffer, 2 blocks/CU, single barrier per K-step.
__global__ __launch_bounds__(256, 2) void qkv_gemm(
    const u16* __restrict__ xb,
    const u16* __restrict__ wqb, const u16* __restrict__ wkb, const u16* __restrict__ wvb,
    const float* __restrict__ bq, const float* __restrict__ bk, const float* __restrict__ bv,
    u16* __restrict__ Q, u16* __restrict__ K, u16* __restrict__ Vt) {
  __shared__ u16 S[4][128 * 64];     // A0 A1 B0 B1 = 64 KB
  const int id  = blockIdx.x;
  const int mg  = id & 7;            // XCD-owned m-group
  const int mti = mg * 4 + ((id >> 3) & 3);   // m tile 0..31
  const int rr  = id >> 5;           // 0..23
  const int x8  = rr & 7;            // n tile
  const int mat = rr >> 3;           // 0=Q 1=K 2=V
  const int n0  = x8 * 128;
  const int m0  = mti * 128;
  const u16*   W    = (mat == 0) ? wqb : (mat == 1) ? wkb : wvb;
  const float* bias = (mat == 0) ? bq  : (mat == 1) ? bk  : bv;

  const int tid = threadIdx.x, wave = tid >> 6, lane = tid & 63;
  const int quad = lane >> 4, l15 = lane & 15;
  const int wm = wave >> 1, wn = wave & 1;

  const u16* A_tile = xb + (size_t)m0 * NC;
  const u16* W_tile = W  + (size_t)n0 * NC;

  const int srow = (lane >> 3);                 // 0..7 within wave's 8-row group
  const int sgc  = (lane & 7) ^ srow;           // swizzled global chunk
  int sOff[4], sLds[4];
#pragma unroll
  for (int ii = 0; ii < 4; ii++) {
    int row_l = ii * 32 + wave * 8 + srow;
    sOff[ii] = row_l * NC + sgc * 8;
    sLds[ii] = (ii * 32 + wave * 8) * 64;       // wave-uniform LDS base (u16)
  }

  float4v acc[4][4];
#pragma unroll
  for (int i = 0; i < 4; i++)
#pragma unroll
    for (int j = 0; j < 4; j++) acc[i][j] = (float4v){0.f, 0.f, 0.f, 0.f};

  auto stage = [&](int ki, int p) {
    const u16* a = A_tile + ki * 64;
    const u16* w = W_tile + ki * 64;
#pragma unroll
    for (int ii = 0; ii < 4; ii++) {
      gld_lds16(a + sOff[ii], S[p]     + sLds[ii]);
      gld_lds16(w + sOff[ii], S[2 + p] + sLds[ii]);
    }
  };

  stage(0, 0);
  for (int ki = 0; ki < 16; ki++) {
    const int p = ki & 1;
    WB0;                            // own stage(ki) drained, then barrier
    if (ki < 15) stage(ki + 1, p ^ 1);   // overwrite p^1: its readers passed barrier
    const u16* As = S[p];
    const u16* Bs = S[2 + p];
#pragma unroll
    for (int kk = 0; kk < 2; kk++) {
      short8 af[4], bf[4];
#pragma unroll
      for (int mt = 0; mt < 4; mt++) {
        int row = wm * 64 + mt * 16 + l15;
        int e   = (kk * 4 + quad) ^ (row & 7);
        af[mt] = *(const short8*)(As + row * 64 + e * 8);
      }
#pragma unroll
      for (int nt = 0; nt < 4; nt++) {
        int row = wn * 64 + nt * 16 + l15;
        int e   = (kk * 4 + quad) ^ (row & 7);
        bf[nt] = *(const short8*)(Bs + row * 64 + e * 8);
      }
#pragma unroll
      for (int mt = 0; mt < 4; mt++)
#pragma unroll
        for (int nt = 0; nt < 4; nt++)
          acc[mt][nt] = __builtin_amdgcn_mfma_f32_16x16x32_bf16(af[mt], bf[nt], acc[mt][nt], 0, 0, 0);
    }
  }

  if (mat != 2) {
    // Q/K: repack via LDS, then coalesced 16B stores. Bank swizzle: XOR col bits
    // 4..6 with (row>>2)&7 so the 4 quad-rows of one store land in distinct 32B
    // segments.
    u16* dst = (mat == 0) ? Q : K;
    const float osc = (mat == 0) ? 0.18033688f : 1.0f;   // fold 0.125*log2(e) into Q
    BAR_PLAIN;                       // all waves done reading S before reuse
    u16* tile = (u16*)S;             // [128 rows][128 cols] u16, swizzled
#pragma unroll
    for (int nt = 0; nt < 4; nt++) {
      int col = wn * 64 + nt * 16 + l15;
      float bval = bias[n0 + col];
#pragma unroll
      for (int mt = 0; mt < 4; mt++) {
        int rowb = wm * 64 + mt * 16 + quad * 4;
#pragma unroll
        for (int r = 0; r < 4; r++) {
          int row = rowb + r;
          tile[row * 128 + (col ^ (((row >> 2) & 7) << 4))] =
              f2bf((acc[mt][nt][r] + bval) * osc);
        }
      }
    }
    __syncthreads();
#pragma unroll
    for (int it = 0; it < 8; it++) {
      int idx = it * 256 + tid;      // 0..2047: 128 rows x 16 col-chunks of 16B
      int row = idx >> 4, ck = idx & 15;
      int s = (row >> 2) & 7;
      short8 v = *(const short8*)(tile + row * 128 + ((((ck >> 1) ^ s) << 4) | ((ck & 1) << 3)));
      *(short8*)(dst + (size_t)(m0 + row) * NC + n0 + ck * 8) = v;
    }
  } else {
    // V: transpose + s-permute via LDS.
    BAR_PLAIN;                       // all waves done reading S before reuse
    u16* tile = (u16*)S;
#pragma unroll
    for (int nt = 0; nt < 4; nt++) {
      int c = wn * 64 + nt * 16 + l15;
      float bval = bias[n0 + c];
#pragma unroll
      for (int mt = 0; mt < 4; mt++) {
#pragma unroll
        for (int r = 0; r < 4; r++) {
          int mr  = mt * 4 + r;
          int off = wm * 64 + quad * 16 + mr;          // permuted t position
          int ck  = (off >> 3) ^ (c & 15);
          tile[c * 128 + ck * 8 + (off & 7)] = f2bf(acc[mt][nt][r] + bval);
        }
      }
    }
    __syncthreads();
    const int b  = m0 >> 11, t0 = m0 & 2047;
    const int bh0 = b * NH + (n0 >> 6);
#pragma unroll
    for (int it = 0; it < 8; it++) {
      int idx = it * 256 + tid;      // 0..2047 chunks of 16 B
      int c = idx >> 4, ck = idx & 15;
      short8 v = *(const short8*)(tile + c * 128 + ((ck ^ (c & 15)) * 8));
      *(short8*)(Vt + ((size_t)(bh0 + (c >> 6)) * ND + (c & 63)) * NT + t0 + ck * 8) = v;
    }
  }
}

// ---------------- flash attention (causal), fixed-max softmax, NO SPLITS --------
// 64-ROW Q-BLOCKS: 32 q-tiles/bh, tile t' needs exactly t'+1 kv-chunks (1..32,
// total 528/bh = 3% less than the old split scheme's 544). Every block computes
// a COMPLETE softmax row -> no partials, no Opart/Lpart, no combine kernel, one
// fewer launch boundary. grid 1024 = 8 bh-low x 32 classes x 4 passes; 4
// blocks/CU; 16 waves/CU TLP preserved (r5: attn's latency hider).
// LOAD BALANCE: 8 quadruples of q-tiles {31,0,30,1},{29,2,28,3},... each
// summing to exactly 66 kv-chunk-units; pass-rotation keeps each (cls,bh)
// computed exactly once and gives every CU one full quadruple.
// Per wave: 16 q-rows. Only the diagonal chunk (i==cls) is masked: wave w
// computes subs 0..w (sub w with in-sub mask quad*4+r > l15; subs >w emit P=0).
__global__ __launch_bounds__(256, 4) void attn(
    const u16* __restrict__ Q, const u16* __restrict__ K,
    const u16* __restrict__ Vt, u16* __restrict__ O) {
  __shared__ u16 Kc[2][64 * 64];   // [s][d] swizzled
  __shared__ u16 Vc[2][64 * 64];   // [d][pos(s)] swizzled

  const int tid = threadIdx.x, wave = tid >> 6, lane = tid & 63;
  const int quad = lane >> 4, l15 = lane & 15;
  const int c8 = lane & 7, r8 = lane >> 3;
  const int id = blockIdx.x;
  const int gq = (id >> 3) & 31;   // class-group (same for a CU's 4 blocks)
  const int gp = id >> 8;          // pass 0..3
  // quadruples of q-tile indices t' (iters = t'+1): each row sums to 66 iters.
  static const uint8_t QT[8][4] = {
      {31, 0, 30, 1}, {29, 2, 28, 3}, {27, 4, 26, 5}, {25, 6, 24, 7},
      {23, 8, 22, 9}, {21, 10, 20, 11}, {19, 12, 18, 13}, {17, 14, 16, 15}};
  const int cls = QT[gq >> 2][((gq & 3) + gp) & 3];   // q-tile 0..31 (64 rows)
  const int bh = (id & 7) + 8 * gp;
  const int b = bh >> 4, h = bh & 15;
  const int qb0 = cls * 64 + wave * 16;   // this wave's 16 q-rows
  const int c_hi = cls;                   // kv chunks 0..cls (diag = cls)

  short8 qf[2];
  {
    const u16* qrow = Q + (size_t)(b * NT + qb0 + l15) * NC + h * ND + quad * 8;
    qf[0] = *(const short8*)(qrow);
    qf[1] = *(const short8*)(qrow + 32);
  }

  const short4v vone = {(short)0x3F80, (short)0x3F80, (short)0x3F80, (short)0x3F80};
  float4v l_acc = (float4v){0.f, 0.f, 0.f, 0.f};
  float4v o_acc[4];
#pragma unroll
  for (int dt = 0; dt < 4; dt++) o_acc[dt] = (float4v){0.f, 0.f, 0.f, 0.f};

  // staging: 256 threads cover 64 rows x 64 cols; row = wave*16 + ii*8 + r8,
  // chunk c8 ^ (row&7) -- identical pattern to the split version.
  int kOff[2], vOff[2], ldsOff[2];
#pragma unroll
  for (int ii = 0; ii < 2; ii++) {
    int row = wave * 16 + ii * 8 + r8;
    int gc  = c8 ^ (row & 7);
    kOff[ii]   = row * NC + gc * 8;
    vOff[ii]   = row * NT + gc * 8;
    ldsOff[ii] = (wave * 16 + ii * 8) * 64;
  }
  const u16* Kbase = K  + (size_t)b * NT * NC + h * ND;
  const u16* Vbase = Vt + (size_t)bh * ND * NT;

  auto stage = [&](int ci) {
    const int p = ci & 1;
    const u16* kc = Kbase + (size_t)ci * (64 * NC);
    const u16* vc = Vbase + ci * 64;
#pragma unroll
    for (int ii = 0; ii < 2; ii++) {
      gld_lds16(kc + kOff[ii], Kc[p] + ldsOff[ii]);
      gld_lds16(vc + vOff[ii], Vc[p] + ldsOff[ii]);
    }
  };

  stage(0);
  for (int i = 0; i <= c_hi; i++) {
    const int p = i & 1;
    WB0;                            // own stage(i) drained, then barrier
    if (i < c_hi) stage(i + 1);     // into p^1: its readers passed the barrier
    const u16* Ks = Kc[p];
    const u16* Vs = Vc[p];
    const bool diag = (i == c_hi);  // block-uniform: only chunk with masking
    __builtin_amdgcn_s_setprio(1);

    // per sub: QK^T -> exp2 -> pack. Diagonal: wave w owns subs 0..w.
    short4v pf[4];
#pragma unroll
    for (int sub = 0; sub < 4; sub++) {
      if (!diag || sub <= wave) {     // wave-uniform guard
        float4v a = (float4v){0.f, 0.f, 0.f, 0.f};
#pragma unroll
        for (int kk = 0; kk < 2; kk++) {
          int row = sub * 16 + l15;
          int ch  = (kk * 4 + quad) ^ (row & 7);
          short8 kf = *(const short8*)(Ks + row * 64 + ch * 8);
          a = __builtin_amdgcn_mfma_f32_16x16x32_bf16(kf, qf[kk], a, 0, 0, 0);
        }
        if (diag && sub == wave) {
          // in-sub causal mask: local kv pos (quad*4+r) vs local q pos (l15)
          float pv[4];
#pragma unroll
          for (int r = 0; r < 4; r++) {
            float pp = EXP2(a[r]);
            if ((quad * 4 + r) > l15) pp = 0.f;
            pv[r] = pp;
          }
          pf[sub] = pack4bf(pv[0], pv[1], pv[2], pv[3]);
        } else {
          pf[sub] = pack4bf(EXP2(a[0]), EXP2(a[1]), EXP2(a[2]), EXP2(a[3]));
        }
      } else {
        pf[sub] = (short4v){0, 0, 0, 0};   // fully-masked sub: P == 0
      }
    }

    // l on the MFMA pipe: ones^T * P^T accumulates row sums (idle-pipe work)
    l_acc = MFMA16(vone, pf[0], l_acc);
    l_acc = MFMA16(vone, pf[1], l_acc);
    l_acc = MFMA16(vone, pf[2], l_acc);
    l_acc = MFMA16(vone, pf[3], l_acc);

    // O^T += V^T * P^T : vf = 2 b128/dt (permuted layout)
#pragma unroll
    for (int dt = 0; dt < 4; dt++) {
      int row = dt * 16 + l15;
      int swz = row & 7;
      short8 vA = *(const short8*)(Vs + row * 64 + ((2 * quad)     ^ swz) * 8); // subs 0,1
      short8 vB = *(const short8*)(Vs + row * 64 + ((2 * quad + 1) ^ swz) * 8); // subs 2,3
      short4v vA0 = __builtin_shufflevector(vA, vA, 0, 1, 2, 3);
      short4v vA1 = __builtin_shufflevector(vA, vA, 4, 5, 6, 7);
      short4v vB0 = __builtin_shufflevector(vB, vB, 0, 1, 2, 3);
      short4v vB1 = __builtin_shufflevector(vB, vB, 4, 5, 6, 7);
      o_acc[dt] = MFMA16(vA0, pf[0], o_acc[dt]);
      o_acc[dt] = MFMA16(vA1, pf[1], o_acc[dt]);
      o_acc[dt] = MFMA16(vB0, pf[2], o_acc[dt]);
      o_acc[dt] = MFMA16(vB1, pf[3], o_acc[dt]);
    }
    __builtin_amdgcn_s_setprio(0);
  }

  // l replicated in every l_acc register (rows of ones^T*P^T are identical);
  // complete row -> normalize and store final O directly.
  float inv_l = 1.f / l_acc[0];
  const size_t orow = (size_t)(b * NT + qb0 + l15) * NC + h * ND;
#pragma unroll
  for (int dt = 0; dt < 4; dt++)
    *(short4v*)(O + orow + dt * 16 + quad * 4) =
        pack4bf(o_acc[dt][0] * inv_l, o_acc[dt][1] * inv_l,
                o_acc[dt][2] * inv_l, o_acc[dt][3] * inv_l);
}

// ---------------- output projection: 64x128 tiles, BK=64, single-barrier ------
__global__ __launch_bounds__(256, 2) void out_gemm(
    const u16* __restrict__ Ob, const u16* __restrict__ wpb,
    const float* __restrict__ bp, float* __restrict__ out) {
  __shared__ u16 Sa[2][64 * 64];    // 16 KB
  __shared__ u16 Sb[2][128 * 64];   // 32 KB
  const int n0 = blockIdx.x * 128;
  const int m0 = blockIdx.y * 64;
  const int tid = threadIdx.x, wave = tid >> 6, lane = tid & 63;
  const int quad = lane >> 4, l15 = lane & 15;
  const int wm = wave >> 1, wn = wave & 1;

  const u16* A_tile = Ob  + (size_t)m0 * NC;
  const u16* W_tile = wpb + (size_t)n0 * NC;

  const int srow = (lane >> 3);
  const int sgc  = (lane & 7) ^ srow;
  int sOff[4], sLds[4];
#pragma unroll
  for (int ii = 0; ii < 4; ii++) {
    int row_l = ii * 32 + wave * 8 + srow;
    sOff[ii] = row_l * NC + sgc * 8;
    sLds[ii] = (ii * 32 + wave * 8) * 64;
  }

  float4v acc[2][4];
#pragma unroll
  for (int i = 0; i < 2; i++)
#pragma unroll
    for (int j = 0; j < 4; j++) acc[i][j] = (float4v){0.f, 0.f, 0.f, 0.f};

  auto stage = [&](int ki, int p) {
    const u16* a = A_tile + ki * 64;
    const u16* w = W_tile + ki * 64;
#pragma unroll
    for (int ii = 0; ii < 2; ii++)
      gld_lds16(a + sOff[ii], Sa[p] + sLds[ii]);
#pragma unroll
    for (int ii = 0; ii < 4; ii++)
      gld_lds16(w + sOff[ii], Sb[p] + sLds[ii]);
  };

  stage(0, 0);
  for (int ki = 0; ki < 16; ki++) {
    const int p = ki & 1;
    WB0;
    if (ki < 15) stage(ki + 1, p ^ 1);
#pragma unroll
    for (int kk = 0; kk < 2; kk++) {
      short8 af[2], bf[4];
#pragma unroll
      for (int mt = 0; mt < 2; mt++) {
        int row = wm * 32 + mt * 16 + l15;
        int e   = (kk * 4 + quad) ^ (row & 7);
        af[mt] = *(const short8*)(Sa[p] + row * 64 + e * 8);
      }
#pragma unroll
      for (int nt = 0; nt < 4; nt++) {
        int row = wn * 64 + nt * 16 + l15;
        int e   = (kk * 4 + quad) ^ (row & 7);
        bf[nt] = *(const short8*)(Sb[p] + row * 64 + e * 8);
      }
#pragma unroll
      for (int mt = 0; mt < 2; mt++)
#pragma unroll
        for (int nt = 0; nt < 4; nt++)
          acc[mt][nt] = __builtin_amdgcn_mfma_f32_16x16x32_bf16(af[mt], bf[nt], acc[mt][nt], 0, 0, 0);
    }
  }

#pragma unroll
  for (int nt = 0; nt < 4; nt++) {
    int col = n0 + wn * 64 + nt * 16 + l15;
    float bval = bp[col];
#pragma unroll
    for (int mt = 0; mt < 2; mt++) {
      int rowb = m0 + wm * 32 + mt * 16 + quad * 4;
#pragma unroll
      for (int r = 0; r < 4; r++)
        out[(rowb + r) * NC + col] = acc[mt][nt][r] + bval;
    }
  }
}

extern "C" void kernel_launch(void* const* d_in, const int* in_sizes, int n_in,
                              void* d_out, int out_size, void* d_ws, size_t ws_size,
                              hipStream_t stream) {
  // setup_inputs order: x, Wk, bk, Wq, bq, Wv, bv, Wp, bp
  const float* x  = (const float*)d_in[0];
  const float* Wk = (const float*)d_in[1];
  const float* bk = (const float*)d_in[2];
  const float* Wq = (const float*)d_in[3];
  const float* bq = (const float*)d_in[4];
  const float* Wv = (const float*)d_in[5];
  const float* bv = (const float*)d_in[6];
  const float* Wp = (const float*)d_in[7];
  const float* bp = (const float*)d_in[8];
  float* out = (float*)d_out;

  uint8_t* ws = (uint8_t*)d_ws;
  const size_t MB = 1u << 20;
  // layout: xb[0,8) wk[8,10) wq[10,12) wv[12,14) wp[14,16) — xb/wk/wq/wv die
  // after qkv. wpb [14,16) stays live for out_gemm. No Opart/Lpart anymore
  // (attn computes complete rows -> writes Ob directly).
  u16* xb    = (u16*)(ws + 0 * MB);
  u16* wkb   = (u16*)(ws + 8 * MB);
  u16* wqb   = (u16*)(ws + 10 * MB);
  u16* wvb   = (u16*)(ws + 12 * MB);
  u16* wpb   = (u16*)(ws + 14 * MB);
  u16* Qb    = (u16*)(ws + 16 * MB);
  u16* Kb    = (u16*)(ws + 24 * MB);
  u16* Vtb   = (u16*)(ws + 32 * MB);   // [B,H,D,T'] (s-permuted in 64-chunks)
  u16* Ob    = (u16*)(ws + 40 * MB);   // attention output

  cast_all<<<8192, 256, 0, stream>>>(x, Wk, Wq, Wv, Wp, xb, wkb, wqb, wvb, wpb);
  qkv_gemm<<<768, 256, 0, stream>>>(xb, wqb, wkb, wvb, bq, bk, bv, Qb, Kb, Vtb);
  attn<<<1024, 256, 0, stream>>>(Qb, Kb, Vtb, Ob);
  out_gemm<<<dim3(8, 64), 256, 0, stream>>>(Ob, wpb, bp, out);
}